// Round 2
// baseline (1981.355 us; speedup 1.0000x reference)
//
#include <hip/hip_runtime.h>
#include <hip/hip_bf16.h>
#include <math.h>

// Problem dims (fixed by reference)
#define BB 4
#define SS 2048
#define EE 256
#define HH 8
#define DD 32
#define LL 2
#define NI 1024
#define NROWS (BB*SS)   // 8192

// ---------------------------------------------------------------------------
// Embedding: h[row,:] = wte[ids[row],:] + wpe[row % S,:]
// grid = NROWS blocks of 64 threads; each thread handles 4 contiguous floats.
__global__ __launch_bounds__(64) void embed_kernel(
    const int* __restrict__ ids, const float* __restrict__ wte,
    const float* __restrict__ wpe, float* __restrict__ h)
{
    int row  = blockIdx.x;            // b*S + s
    int s    = row & (SS - 1);
    int lane = threadIdx.x;
    int id   = ids[row];
    float4 a = *(const float4*)(wte + (size_t)id * EE + lane * 4);
    float4 p = *(const float4*)(wpe + (size_t)s  * EE + lane * 4);
    float4 o = { a.x + p.x, a.y + p.y, a.z + p.z, a.w + p.w };
    *(float4*)(h + (size_t)row * EE + lane * 4) = o;
}

// ---------------------------------------------------------------------------
// LayerNorm over E=256: one wave (64 lanes) per row, 4 floats/lane.
__global__ __launch_bounds__(64) void ln_kernel(
    const float* __restrict__ in, const float* __restrict__ g,
    const float* __restrict__ b, float* __restrict__ out)
{
    int row  = blockIdx.x;
    int lane = threadIdx.x;
    float4 v = *(const float4*)(in + (size_t)row * EE + lane * 4);
    float s  = v.x + v.y + v.z + v.w;
    float ss = v.x*v.x + v.y*v.y + v.z*v.z + v.w*v.w;
    #pragma unroll
    for (int off = 32; off; off >>= 1) {
        s  += __shfl_xor(s,  off);
        ss += __shfl_xor(ss, off);
    }
    float mu  = s * (1.f / EE);
    float var = ss * (1.f / EE) - mu * mu;
    float rs  = rsqrtf(var + 1e-5f);
    float4 gv = *(const float4*)(g + lane * 4);
    float4 bv = *(const float4*)(b + lane * 4);
    float4 o;
    o.x = (v.x - mu) * rs * gv.x + bv.x;
    o.y = (v.y - mu) * rs * gv.y + bv.y;
    o.z = (v.z - mu) * rs * gv.z + bv.z;
    o.w = (v.w - mu) * rs * gv.w + bv.w;
    *(float4*)(out + (size_t)row * EE + lane * 4) = o;
}

// ---------------------------------------------------------------------------
// Tiled f32 GEMM: C[M,N] = act( A[M,K] @ B[K,N] + bias [+ res] )
// BM=BN=64, BK=16, 256 threads, 4x4 micro-tile per thread.
// All dims divide evenly (M=8192, N in {256,768,1024}, K in {256,1024}).
template<bool GELU_ACT, bool RES>
__global__ __launch_bounds__(256) void gemm_kernel(
    const float* __restrict__ A, const float* __restrict__ Bm,
    const float* __restrict__ bias, const float* __restrict__ res,
    float* __restrict__ C, int M, int N, int K)
{
    const int Bb = 64, BK = 16;
    __shared__ float As[16][64];
    __shared__ float Bs[16][64];
    int tid = threadIdx.x;
    int bx = blockIdx.x, by = blockIdx.y;
    int tx = tid & 15, ty = tid >> 4;

    float acc[4][4] = {};

    int arow = tid >> 2;        // 0..63  (row within A tile)
    int akq  = tid & 3;         // which float4 of the 16 k's
    int brow = tid >> 4;        // 0..15  (k within B tile)
    int bcq  = tid & 15;        // which float4 of the 64 cols

    const float* Aptr = A + (size_t)(by * Bb + arow) * K + akq * 4;
    const float* Bptr = Bm + (size_t)brow * N + bx * Bb + bcq * 4;

    for (int k0 = 0; k0 < K; k0 += BK) {
        float4 av = *(const float4*)(Aptr + k0);
        As[akq*4+0][arow] = av.x;
        As[akq*4+1][arow] = av.y;
        As[akq*4+2][arow] = av.z;
        As[akq*4+3][arow] = av.w;
        float4 bv = *(const float4*)(Bptr + (size_t)k0 * N);
        *(float4*)&Bs[brow][bcq*4] = bv;
        __syncthreads();
        #pragma unroll
        for (int k = 0; k < BK; ++k) {
            float a[4], b[4];
            #pragma unroll
            for (int i = 0; i < 4; ++i) a[i] = As[k][ty*4+i];
            #pragma unroll
            for (int j = 0; j < 4; ++j) b[j] = Bs[k][tx*4+j];
            #pragma unroll
            for (int i = 0; i < 4; ++i)
                #pragma unroll
                for (int j = 0; j < 4; ++j)
                    acc[i][j] += a[i] * b[j];
        }
        __syncthreads();
    }

    #pragma unroll
    for (int i = 0; i < 4; ++i) {
        int r  = by * Bb + ty * 4 + i;
        int c0 = bx * Bb + tx * 4;
        float4 outv;
        float* po = &outv.x;
        #pragma unroll
        for (int j = 0; j < 4; ++j) {
            float v = acc[i][j] + bias[c0 + j];
            if (RES) v += res[(size_t)r * N + c0 + j];
            if (GELU_ACT) {
                float t = v;
                v = 0.5f * t * (1.f + tanhf(0.7978845608028654f * (t + 0.044715f * t * t * t)));
            }
            po[j] = v;
        }
        *(float4*)&C[(size_t)r * N + c0] = outv;
    }
}

// ---------------------------------------------------------------------------
// Causal flash attention, f32. qkv layout: [row=b*S+s][768] with q|k|v slices.
// One wave per 64 q-rows of one (b,h); K/V tiles staged in LDS; per-thread
// online softmax (masked entries skipped: exp(-10000-m) == 0 in f32).
__global__ __launch_bounds__(64) void attn_kernel(
    const float* __restrict__ qkv, float* __restrict__ out)
{
    __shared__ float Ks[64][32];
    __shared__ float Vs[64][32];
    int lane = threadIdx.x;
    int qb = blockIdx.x, hh = blockIdx.y, b = blockIdx.z;
    int qrow = qb * 64 + lane;   // s index of this thread's query

    const float* qptr = qkv + ((size_t)(b * SS + qrow)) * (3*EE) + hh * DD;
    float q[DD];
    #pragma unroll
    for (int d = 0; d < DD; d += 4) {
        float4 t = *(const float4*)(qptr + d);
        q[d] = t.x; q[d+1] = t.y; q[d+2] = t.z; q[d+3] = t.w;
    }
    float o[DD];
    #pragma unroll
    for (int d = 0; d < DD; ++d) o[d] = 0.f;
    float m = -INFINITY, l = 0.f;
    const float scale = 0.17677669529663687f;  // 1/sqrt(32)

    for (int kb = 0; kb <= qb; ++kb) {
        int kstart = kb * 64;
        const float* kbase = qkv + ((size_t)(b * SS + kstart)) * (3*EE) + hh * DD + EE;
        const float* vbase = kbase + EE;
        #pragma unroll
        for (int i = 0; i < 8; ++i) {
            int j  = lane + i * 64;   // 0..511 (64 rows x 8 float4)
            int r  = j >> 3, d4 = j & 7;
            *(float4*)&Ks[r][d4*4] = *(const float4*)(kbase + (size_t)r * (3*EE) + d4 * 4);
            *(float4*)&Vs[r][d4*4] = *(const float4*)(vbase + (size_t)r * (3*EE) + d4 * 4);
        }
        __syncthreads();

        int jmax = min(64, qrow - kstart + 1);
        for (int j = 0; j < jmax; ++j) {
            float s = 0.f;
            #pragma unroll
            for (int d = 0; d < DD; ++d) s += q[d] * Ks[j][d];  // broadcast LDS reads
            s *= scale;
            float newm = fmaxf(m, s);
            if (newm > m) {
                float corr = expf(m - newm);   // expf(-inf)=0 handles first element
                l *= corr;
                #pragma unroll
                for (int d = 0; d < DD; ++d) o[d] *= corr;
                m = newm;
            }
            float p = expf(s - m);
            l += p;
            #pragma unroll
            for (int d = 0; d < DD; ++d) o[d] += p * Vs[j][d];
        }
        __syncthreads();
    }

    float inv = 1.f / l;
    float* optr = out + ((size_t)(b * SS + qrow)) * EE + hh * DD;
    #pragma unroll
    for (int d = 0; d < DD; d += 4) {
        float4 t;
        t.x = o[d]*inv; t.y = o[d+1]*inv; t.z = o[d+2]*inv; t.w = o[d+3]*inv;
        *(float4*)(optr + d) = t;
    }
}

// ---------------------------------------------------------------------------
extern "C" void kernel_launch(void* const* d_in, const int* in_sizes, int n_in,
                              void* d_out, int out_size, void* d_ws, size_t ws_size,
                              hipStream_t stream)
{
    const int*   ids    = (const int*)  d_in[0];
    const float* wte    = (const float*)d_in[1];
    const float* wpe    = (const float*)d_in[2];
    const float* ln1_g  = (const float*)d_in[3];
    const float* ln1_b  = (const float*)d_in[4];
    const float* qkv_w  = (const float*)d_in[5];
    const float* qkv_b  = (const float*)d_in[6];
    const float* proj_w = (const float*)d_in[7];
    const float* proj_b = (const float*)d_in[8];
    const float* ln2_g  = (const float*)d_in[9];
    const float* ln2_b  = (const float*)d_in[10];
    const float* fc1_w  = (const float*)d_in[11];
    const float* fc1_b  = (const float*)d_in[12];
    const float* fc2_w  = (const float*)d_in[13];
    const float* fc2_b  = (const float*)d_in[14];
    const float* lnf_g  = (const float*)d_in[15];
    const float* lnf_b  = (const float*)d_in[16];

    float* ws    = (float*)d_ws;
    float* h     = ws;                       // 8192*256
    float* x     = h     + (size_t)NROWS*EE; // 8192*256
    float* qkv   = x     + (size_t)NROWS*EE; // 8192*768
    float* attno = qkv   + (size_t)NROWS*3*EE; // 8192*256
    float* m1    = attno + (size_t)NROWS*EE; // 8192*1024

    embed_kernel<<<NROWS, 64, 0, stream>>>(ids, wte, wpe, h);

    for (int l = 0; l < LL; ++l) {
        // x = LN1(h)
        ln_kernel<<<NROWS, 64, 0, stream>>>(h, ln1_g + l*EE, ln1_b + l*EE, x);
        // qkv = x @ Wqkv + bqkv     [8192,256]@[256,768]
        gemm_kernel<false,false><<<dim3(3*EE/64, NROWS/64), 256, 0, stream>>>(
            x, qkv_w + (size_t)l*EE*3*EE, qkv_b + (size_t)l*3*EE, nullptr,
            qkv, NROWS, 3*EE, EE);
        // attno = attention(qkv)
        attn_kernel<<<dim3(SS/64, HH, BB), 64, 0, stream>>>(qkv, attno);
        // h = h + attno @ Wp + bp   [8192,256]@[256,256]
        gemm_kernel<false,true><<<dim3(EE/64, NROWS/64), 256, 0, stream>>>(
            attno, proj_w + (size_t)l*EE*EE, proj_b + (size_t)l*EE, h,
            h, NROWS, EE, EE);
        // x = LN2(h)
        ln_kernel<<<NROWS, 64, 0, stream>>>(h, ln2_g + l*EE, ln2_b + l*EE, x);
        // m1 = gelu(x @ W1 + b1)    [8192,256]@[256,1024]
        gemm_kernel<true,false><<<dim3(NI/64, NROWS/64), 256, 0, stream>>>(
            x, fc1_w + (size_t)l*EE*NI, fc1_b + (size_t)l*NI, nullptr,
            m1, NROWS, NI, EE);
        // h = h + m1 @ W2 + b2      [8192,1024]@[1024,256]
        gemm_kernel<false,true><<<dim3(EE/64, NROWS/64), 256, 0, stream>>>(
            m1, fc2_w + (size_t)l*NI*EE, fc2_b + (size_t)l*EE, h,
            h, NROWS, EE, NI);
    }

    // out = LN_f(h)
    ln_kernel<<<NROWS, 64, 0, stream>>>(h, lnf_g, lnf_b, (float*)d_out);
}